// Round 2
// baseline (380.122 us; speedup 1.0000x reference)
//
#include <hip/hip_runtime.h>
#include <math.h>

#define TT 32
#define EPSF 1e-9f

constexpr int BLOCK = 256;
constexpr int GRID  = 2048;

// Quad-lane broadcast-xor via DPP quad_perm (pure VALU, avoids ds_swizzle).
// XOR1: [1,0,3,2] = 0xB1   XOR2: [2,3,0,1] = 0x4E
template <int CTRL>
__device__ __forceinline__ float dpp_xor(float x) {
    return __int_as_float(__builtin_amdgcn_update_dpp(
        0, __float_as_int(x), CTRL, 0xF, 0xF, true));
}
#define XOR1 0xB1
#define XOR2 0x4E

// Kernel 1: per-block partial sums of (loss * sw) and (sw), double2 per block.
// Layout: 4 lanes per row, lane j owns elements [8j, 8j+8). Quads are
// 4-aligned so DPP quad_perm reductions stay within one row's lanes.
__global__ __launch_bounds__(BLOCK) void nll_partial(
    const float* __restrict__ preds,
    const int*   __restrict__ targets,
    const float* __restrict__ weight,
    const float* __restrict__ sample_weight,
    double*      __restrict__ partials,   // [gridDim.x * 2]
    int N)
{
    __shared__ float w_sh[TT];
    __shared__ float wcm_sh[TT];
    __shared__ double red_l[BLOCK / 64];
    __shared__ double red_s[BLOCK / 64];

    const int tid = threadIdx.x;

    if (tid < TT) w_sh[tid] = weight[tid];
    __syncthreads();
    if (tid < TT) {
        float s = 0.f;
        for (int t = 0; t <= tid; ++t) s += w_sh[t];
        wcm_sh[tid] = s / (float)(tid + 1);
    }
    __syncthreads();

    const int j    = tid & 3;       // lane within 4-lane row group (quad)
    const int base = 8 * j;         // first element index this lane owns

    long long g = (long long)blockIdx.x * (BLOCK / 4) + (tid >> 2);
    const long long stride = (long long)gridDim.x * (BLOCK / 4);

    float acc_loss = 0.f;   // every lane accumulates (x4 duplicate, scaled later)
    float acc_sw   = 0.f;

    const float4* preds4   = (const float4*)preds;
    const int2*   targets2 = (const int2*)targets;

    for (long long row = g; row < (long long)N; row += stride) {
        // 2x float4 per lane; wave covers 16 consecutive rows = 2 KB contiguous
        float4 a = preds4[row * 8 + 2 * j];
        float4 b = preds4[row * 8 + 2 * j + 1];
        int2 t2  = targets2[row];
        float sw = sample_weight[row];

        // row max
        float m = fmaxf(fmaxf(fmaxf(a.x, a.y), fmaxf(a.z, a.w)),
                        fmaxf(fmaxf(b.x, b.y), fmaxf(b.z, b.w)));
        m = fmaxf(m, dpp_xor<XOR1>(m));
        m = fmaxf(m, dpp_xor<XOR2>(m));

        float e0 = __expf(a.x - m), e1 = __expf(a.y - m);
        float e2 = __expf(a.z - m), e3 = __expf(a.w - m);
        float e4 = __expf(b.x - m), e5 = __expf(b.y - m);
        float e6 = __expf(b.z - m), e7 = __expf(b.w - m);

        // in-lane prefix sums (ps7 = lane total, reused for z)
        float ps0 = e0;
        float ps1 = ps0 + e1;
        float ps2 = ps1 + e2;
        float ps3 = ps2 + e3;
        float ps4 = ps3 + e4;
        float ps5 = ps4 + e5;
        float ps6 = ps5 + e6;
        float ps7 = ps6 + e7;

        float z = ps7;
        z += dpp_xor<XOR1>(z);
        z += dpp_xor<XOR2>(z);
        float inv = __builtin_amdgcn_rcpf(z);

        int d   = t2.x < 0 ? 0 : (t2.x > TT - 1 ? TT - 1 : t2.x);
        int idx = d - base;   // in-lane element index of d (may be out of [0,8))

        // pd_e = e[idx] if idx in [0,8) else 0
        float pd_e = 0.f;
        pd_e = (idx == 0) ? e0 : pd_e;
        pd_e = (idx == 1) ? e1 : pd_e;
        pd_e = (idx == 2) ? e2 : pd_e;
        pd_e = (idx == 3) ? e3 : pd_e;
        pd_e = (idx == 4) ? e4 : pd_e;
        pd_e = (idx == 5) ? e5 : pd_e;
        pd_e = (idx == 6) ? e6 : pd_e;
        pd_e = (idx == 7) ? e7 : pd_e;

        // cdf_e = sum of this lane's elems with global index <= d
        float cdf_e = 0.f;
        cdf_e = (idx >= 0) ? ps0 : cdf_e;
        cdf_e = (idx >= 1) ? ps1 : cdf_e;
        cdf_e = (idx >= 2) ? ps2 : cdf_e;
        cdf_e = (idx >= 3) ? ps3 : cdf_e;
        cdf_e = (idx >= 4) ? ps4 : cdf_e;
        cdf_e = (idx >= 5) ? ps5 : cdf_e;
        cdf_e = (idx >= 6) ? ps6 : cdf_e;
        cdf_e = (idx >= 7) ? ps7 : cdf_e;

        pd_e  += dpp_xor<XOR1>(pd_e);
        pd_e  += dpp_xor<XOR2>(pd_e);
        cdf_e += dpp_xor<XOR1>(cdf_e);
        cdf_e += dpp_xor<XOR2>(cdf_e);

        float p_d = pd_e * inv;
        float cdf = cdf_e * inv;
        float Sd  = fminf(fmaxf(1.0f - cdf, EPSF), 1.0f);

        bool ev    = (t2.y != 0);
        float parg = ev ? p_d : Sd;
        float wt   = ev ? w_sh[d] : wcm_sh[d];

        acc_loss = fmaf(-__logf(parg) * wt, sw, acc_loss);
        acc_sw  += sw;
    }

    // all 64 lanes hold partials (x4 duplicated); butterfly + scale by 0.25
    double dl = (double)acc_loss;
    double ds = (double)acc_sw;
    for (int mask = 1; mask < 64; mask <<= 1) {
        dl += __shfl_xor(dl, mask);
        ds += __shfl_xor(ds, mask);
    }
    dl *= 0.25;
    ds *= 0.25;

    const int lane = tid & 63;
    const int w    = tid >> 6;
    if (lane == 0) { red_l[w] = dl; red_s[w] = ds; }
    __syncthreads();
    if (tid == 0) {
        double L = 0.0, S = 0.0;
        for (int i = 0; i < BLOCK / 64; ++i) { L += red_l[i]; S += red_s[i]; }
        partials[2 * (long long)blockIdx.x + 0] = L;
        partials[2 * (long long)blockIdx.x + 1] = S;
    }
}

// Kernel 2: reduce per-block partials, finalize scalar.
__global__ __launch_bounds__(256) void nll_final(
    const double* __restrict__ partials, int nblocks, float* __restrict__ out)
{
    const int tid = threadIdx.x;
    double sl = 0.0, ss = 0.0;
    for (int i = tid; i < nblocks; i += 256) {
        sl += partials[2 * i + 0];
        ss += partials[2 * i + 1];
    }
    for (int mask = 1; mask < 64; mask <<= 1) {
        sl += __shfl_xor(sl, mask);
        ss += __shfl_xor(ss, mask);
    }
    __shared__ double s_l[4], s_s[4];
    const int w = tid >> 6;
    if ((tid & 63) == 0) { s_l[w] = sl; s_s[w] = ss; }
    __syncthreads();
    if (tid == 0) {
        double L = 0.0, S = 0.0;
        for (int i = 0; i < 4; ++i) { L += s_l[i]; S += s_s[i]; }
        double denom = S > 1e-9 ? S : 1e-9;
        out[0] = (float)(L / denom);
    }
}

extern "C" void kernel_launch(void* const* d_in, const int* in_sizes, int n_in,
                              void* d_out, int out_size, void* d_ws, size_t ws_size,
                              hipStream_t stream) {
    const float* preds         = (const float*)d_in[0];
    const int*   targets       = (const int*)d_in[1];
    const float* weight        = (const float*)d_in[2];
    const float* sample_weight = (const float*)d_in[3];
    float*       out           = (float*)d_out;
    double*      partials      = (double*)d_ws;

    const int N = in_sizes[3];   // sample_weight has N elements

    int grid = GRID;
    size_t need = (size_t)grid * 2 * sizeof(double);
    if (ws_size < need) {
        grid = (int)(ws_size / (2 * sizeof(double)));
        if (grid < 1) grid = 1;
    }

    nll_partial<<<grid, BLOCK, 0, stream>>>(preds, targets, weight, sample_weight, partials, N);
    nll_final<<<1, 256, 0, stream>>>(partials, grid, out);
}